// Round 4
// baseline (1599.931 us; speedup 1.0000x reference)
//
#include <hip/hip_runtime.h>
#include <math.h>

// Swin block, B=32, H=W=64, C=384, heads=12, hd=32, WS=8, SS=4.
// Round 4: 256x128 block tile, 128x64 wave tile (8x4 frags), 3-deep pipeline
// with counted vmcnt; swizzled conflict-free LDS; fused LN kernels.

#define ROWS_TOTAL 131072
#define NWIN_TOTAL 2048

typedef __attribute__((ext_vector_type(8))) __bf16 bf16x8;
typedef __attribute__((ext_vector_type(4))) float f32x4;
typedef __attribute__((ext_vector_type(8))) unsigned short ushort8;

__device__ __forceinline__ unsigned short f2bf(float f) {
  unsigned u = __builtin_bit_cast(unsigned, f);
  u = (u + 0x7fffu + ((u >> 16) & 1u)) >> 16;
  return (unsigned short)u;
}

__device__ __forceinline__ void gload16(const void* g, void* l) {
  __builtin_amdgcn_global_load_lds(
      (const __attribute__((address_space(1))) unsigned int*)g,
      (__attribute__((address_space(3))) unsigned int*)l, 16, 0, 0);
}

__device__ __forceinline__ int gather_row(int win, int t) {
  int b = win >> 6, wi = (win >> 3) & 7, wj = win & 7;
  int gi = (wi * 8 + (t >> 3) + 4) & 63;
  int gj = (wj * 8 + (t & 7) + 4) & 63;
  return (b << 12) + (gi << 6) + gj;
}

// Wave tile 128x64: 8 A-frags x 4 B-frags, 32 MFMA per 32-deep K-step.
// LDS: A tile 256 rows x 32 bf16 (64B rows), B tile 128 rows x 32 bf16.
// Granule slot s of row r holds logical granule s ^ ((r>>1)&3).
__device__ __forceinline__ void frag_mma(const ushort* As_, const ushort* Bs_,
                                         int wr, int wc, int lane,
                                         f32x4 acc[8][4]) {
  const int go = (((lane >> 4) ^ ((lane >> 1) & 3)) << 3);
  const int lr = lane & 15;
  bf16x8 bfr[4];
#pragma unroll
  for (int nj = 0; nj < 4; ++nj)
    bfr[nj] = *(const bf16x8*)(Bs_ + (wc * 64 + nj * 16 + lr) * 32 + go);
#pragma unroll
  for (int mi = 0; mi < 8; ++mi) {
    bf16x8 af = *(const bf16x8*)(As_ + (wr * 128 + mi * 16 + lr) * 32 + go);
#pragma unroll
    for (int nj = 0; nj < 4; ++nj)
      acc[mi][nj] = __builtin_amdgcn_mfma_f32_16x16x32_bf16(
          af, bfr[nj], acc[mi][nj], 0, 0, 0);
  }
}

#define VM6() asm volatile("s_waitcnt vmcnt(6)" ::: "memory")
#define VM0() asm volatile("s_waitcnt vmcnt(0)" ::: "memory")
#define SCB() __builtin_amdgcn_sched_barrier(0)
#define BARR() __builtin_amdgcn_s_barrier()

// Per-wave stage of one 32-deep K-step: 4 A-gloads (64 rows) + 2 B-gloads
// (32 rows). LDS dest linear; global src carries the inverse swizzle (sle).
#define STG(B_, T_)                                    \
  { size_t ko = (size_t)(T_) * 64;                     \
    gload16(aS0 + ko, &As[B_][aD]);                    \
    gload16(aS1 + ko, &As[B_][aD + 512]);              \
    gload16(aS2 + ko, &As[B_][aD + 1024]);             \
    gload16(aS3 + ko, &As[B_][aD + 1536]);             \
    gload16(bS0 + ko, &Bs[B_][bD]);                    \
    gload16(bS1 + ko, &Bs[B_][bD + 512]); }

#define GEMM_PIPE(NK)                                               \
  {                                                                 \
    STG(0, 0);                                                      \
    STG(1, 1);                                                      \
    VM6(); SCB(); BARR(); SCB();                                    \
    int cur = 0;                                                    \
    for (int t = 0; t < (NK); ++t) {                                \
      if (t + 2 < (NK)) {                                           \
        int nb = cur + 2; if (nb >= 3) nb -= 3;                     \
        STG(nb, t + 2);                                             \
      }                                                             \
      __builtin_amdgcn_s_setprio(1);                                \
      frag_mma(&As[cur][0], &Bs[cur][0], wr, wc, lane, acc);        \
      __builtin_amdgcn_s_setprio(0);                                \
      if (t + 2 < (NK)) { VM6(); } else { VM0(); }                  \
      SCB(); BARR(); SCB();                                         \
      ++cur; if (cur == 3) cur = 0;                                 \
    }                                                               \
  }

// ---------------- weight transpose+convert: W[k][n] f32 -> Wt[n][k] bf16 ----
__global__ __launch_bounds__(256) void wprep_k(
    const float* __restrict__ qkvw, const float* __restrict__ projw,
    const float* __restrict__ fc1w, const float* __restrict__ fc2w,
    ushort* __restrict__ wq, ushort* __restrict__ wp,
    ushort* __restrict__ w1, ushort* __restrict__ w2) {
  int gid = blockIdx.x * 256 + threadIdx.x;
  const int S1 = 1152 * 384;
  const int S2 = S1 + 384 * 384;
  const int S3 = S2 + 1536 * 384;
  const int S4 = S3 + 384 * 1536;
  if (gid < S1) {
    int n = gid / 384, k = gid - n * 384;
    wq[gid] = f2bf(qkvw[(size_t)k * 1152 + n]);
  } else if (gid < S2) {
    int i = gid - S1, n = i / 384, k = i - n * 384;
    wp[i] = f2bf(projw[(size_t)k * 384 + n]);
  } else if (gid < S3) {
    int i = gid - S2, n = i / 384, k = i - n * 384;
    w1[i] = f2bf(fc1w[(size_t)k * 1536 + n]);
  } else if (gid < S4) {
    int i = gid - S3, n = i / 1536, k = i - n * 1536;
    w2[i] = f2bf(fc2w[(size_t)k * 384 + n]);
  }
}

// ---------------- fused LN: stats + apply -> bf16, one read of x ----------
__global__ __launch_bounds__(256) void ln_fused_k(
    const float* __restrict__ x, const float* __restrict__ g,
    const float* __restrict__ b, ushort* __restrict__ o) {
  int wid = threadIdx.x >> 6, lane = threadIdx.x & 63;
  int row = (blockIdx.x << 2) + wid;
  const float* p = x + (size_t)row * 384;
  float2 v[3];
  float s = 0.f, ss = 0.f;
#pragma unroll
  for (int c = 0; c < 3; ++c) {
    v[c] = *(const float2*)(p + lane * 2 + c * 128);
    s += v[c].x + v[c].y;
    ss += v[c].x * v[c].x + v[c].y * v[c].y;
  }
#pragma unroll
  for (int off = 1; off < 64; off <<= 1) {
    s += __shfl_xor(s, off);
    ss += __shfl_xor(ss, off);
  }
  float m = s * (1.f / 384.f);
  float r = rsqrtf(ss * (1.f / 384.f) - m * m + 1e-5f);
  ushort* op = o + (size_t)row * 384;
#pragma unroll
  for (int c = 0; c < 3; ++c) {
    float2 gg = *(const float2*)(g + lane * 2 + c * 128);
    float2 bb = *(const float2*)(b + lane * 2 + c * 128);
    union { ushort u[2]; unsigned w; } pk;
    pk.u[0] = f2bf((v[c].x - m) * r * gg.x + bb.x);
    pk.u[1] = f2bf((v[c].y - m) * r * gg.y + bb.y);
    *(unsigned*)(op + lane * 2 + c * 128) = pk.w;
  }
}

// ---------------- QKV GEMM (bf16 MFMA): gathered xln @ WqT ----------------
__global__ __launch_bounds__(256, 2) void qkv_mfma_k(
    const ushort* __restrict__ xln, const ushort* __restrict__ wq,
    const float* __restrict__ qkvb, float* __restrict__ qd,
    float* __restrict__ kd, float* __restrict__ vd, int wc0) {
  __shared__ __align__(16) ushort As[3][8192];
  __shared__ __align__(16) ushort Bs[3][4096];
  __shared__ int rowS[256];
  const int tid = threadIdx.x;
  const int w = tid >> 6, lane = tid & 63;
  const int wr = w >> 1, wc = w & 1;
  const int bm = blockIdx.x, n0 = blockIdx.y * 128;
  {
    int win = wc0 + bm * 4 + (tid >> 6);
    rowS[tid] = gather_row(win, tid & 63);
  }
  __syncthreads();
  const int sle = (((lane & 3) ^ ((lane >> 3) & 3)) << 4);
  const int rb = w * 64 + (lane >> 2);
  const char* aS0 = (const char*)xln + (size_t)rowS[rb] * 768 + sle;
  const char* aS1 = (const char*)xln + (size_t)rowS[rb + 16] * 768 + sle;
  const char* aS2 = (const char*)xln + (size_t)rowS[rb + 32] * 768 + sle;
  const char* aS3 = (const char*)xln + (size_t)rowS[rb + 48] * 768 + sle;
  const int nb = n0 + w * 32 + (lane >> 2);
  const char* bS0 = (const char*)wq + (size_t)nb * 768 + sle;
  const char* bS1 = (const char*)wq + (size_t)(nb + 16) * 768 + sle;
  const int aD = w * 2048 + lane * 8;
  const int bD = w * 1024 + lane * 8;
  f32x4 acc[8][4];
#pragma unroll
  for (int i = 0; i < 8; ++i)
#pragma unroll
    for (int j = 0; j < 4; ++j) acc[i][j] = (f32x4)(0.f);
  GEMM_PIPE(12);
  const float scale = 0.17677669529663687f;
#pragma unroll
  for (int mi = 0; mi < 8; ++mi) {
#pragma unroll
    for (int r = 0; r < 4; ++r) {
      int rr = wr * 128 + mi * 16 + ((lane >> 4) << 2) + r;
      int w_rel = bm * 4 + (rr >> 6), t = rr & 63;
#pragma unroll
      for (int nj = 0; nj < 4; ++nj) {
        int nc = n0 + wc * 64 + nj * 16 + (lane & 15);
        float v = acc[mi][nj][r] + qkvb[nc];
        int qi = nc / 384, rem = nc - qi * 384;
        int hh = rem >> 5, d = rem & 31;
        float* base = (qi == 0) ? qd : (qi == 1 ? kd : vd);
        if (qi == 0) v *= scale;
        base[(((size_t)w_rel * 12 + hh) << 11) + (t << 5) + d] = v;
      }
    }
  }
}

// ---------------- windowed attention (fp32), emits bf16 ----------------
__global__ __launch_bounds__(128) void attn_k(
    const float* __restrict__ q, const float* __restrict__ k,
    const float* __restrict__ v, const float* __restrict__ rpb,
    ushort* __restrict__ ao, int wc0) {
  __shared__ __align__(16) float kbuf[2][64][32];
  __shared__ __align__(16) float vbuf[2][64][32];
  __shared__ float bias[2][232];
  __shared__ int region[64];
  const int tid = threadIdx.x;
  const int wid = tid >> 6, lane = tid & 63;
  const int w = blockIdx.x, win = wc0 + w;
  const int head = blockIdx.y * 2 + wid;
  if (tid < 64) {
    int wi = (win >> 3) & 7, wj = win & 7;
    int pi = wi * 8 + (tid >> 3), pj = wj * 8 + (tid & 7);
    int ri = pi < 56 ? 0 : (pi < 60 ? 1 : 2);
    int rj = pj < 56 ? 0 : (pj < 60 ? 1 : 2);
    region[tid] = ri * 3 + rj;
  }
  const size_t hb = ((size_t)w * 12 + head) * 2048;
  const float* kp = k + hb;
  const float* vp = v + hb;
#pragma unroll
  for (int s = 0; s < 8; ++s) {
    int f = s * 64 + lane;
    int r = f >> 3, c = (f & 7) << 2;
    *(float4*)&kbuf[wid][r][c] = *(const float4*)(kp + r * 32 + c);
    *(float4*)&vbuf[wid][r][c] = *(const float4*)(vp + r * 32 + c);
  }
  for (int s = lane; s < 225; s += 64) bias[wid][s] = rpb[s * 12 + head];
  __syncthreads();
  const int i = lane;
  float qr[32];
  const float* qp = q + hb + (i << 5);
#pragma unroll
  for (int c = 0; c < 32; c += 4) {
    float4 t4 = *(const float4*)(qp + c);
    qr[c] = t4.x; qr[c + 1] = t4.y; qr[c + 2] = t4.z; qr[c + 3] = t4.w;
  }
  const int yi = i >> 3, xi = i & 7, regi = region[i];
  float sc[64];
  float mx = -3.0e38f;
#pragma unroll
  for (int j = 0; j < 64; ++j) {
    float a = 0.f;
#pragma unroll
    for (int c = 0; c < 32; c += 4) {
      float4 kv = *(float4*)&kbuf[wid][j][c];
      a = fmaf(qr[c], kv.x, a);
      a = fmaf(qr[c + 1], kv.y, a);
      a = fmaf(qr[c + 2], kv.z, a);
      a = fmaf(qr[c + 3], kv.w, a);
    }
    int dy = yi - (j >> 3) + 7, dx = xi - (j & 7) + 7;
    a += bias[wid][dy * 15 + dx];
    if (region[j] != regi) a -= 100.f;
    sc[j] = a;
    mx = fmaxf(mx, a);
  }
  float sum = 0.f;
#pragma unroll
  for (int j = 0; j < 64; ++j) {
    float e = __expf(sc[j] - mx);
    sc[j] = e;
    sum += e;
  }
  const float inv = 1.f / sum;
  float o[32];
#pragma unroll
  for (int c = 0; c < 32; ++c) o[c] = 0.f;
#pragma unroll
  for (int j = 0; j < 64; ++j) {
    float p = sc[j];
#pragma unroll
    for (int c = 0; c < 32; c += 4) {
      float4 vv = *(float4*)&vbuf[wid][j][c];
      o[c] = fmaf(p, vv.x, o[c]);
      o[c + 1] = fmaf(p, vv.y, o[c + 1]);
      o[c + 2] = fmaf(p, vv.z, o[c + 2]);
      o[c + 3] = fmaf(p, vv.w, o[c + 3]);
    }
  }
  ushort* op = ao + ((size_t)(w * 64 + i)) * 384 + (head << 5);
#pragma unroll
  for (int c = 0; c < 32; c += 8) {
    ushort8 pk;
#pragma unroll
    for (int j2 = 0; j2 < 8; ++j2) pk[j2] = f2bf(o[c + j2] * inv);
    *(ushort8*)(op + c) = pk;
  }
}

// ---------------- proj GEMM (bf16 MFMA) + unshift scatter + residual --------
__global__ __launch_bounds__(256, 2) void proj_mfma_k(
    const ushort* __restrict__ ao, const ushort* __restrict__ wp,
    const float* __restrict__ pb, const float* __restrict__ x,
    float* __restrict__ x2, int wc0) {
  __shared__ __align__(16) ushort As[3][8192];
  __shared__ __align__(16) ushort Bs[3][4096];
  const int tid = threadIdx.x;
  const int w = tid >> 6, lane = tid & 63;
  const int wr = w >> 1, wc = w & 1;
  const int bm = blockIdx.x, n0 = blockIdx.y * 128;
  const int sle = (((lane & 3) ^ ((lane >> 3) & 3)) << 4);
  const int rb = bm * 256 + w * 64 + (lane >> 2);
  const char* aS0 = (const char*)ao + (size_t)rb * 768 + sle;
  const char* aS1 = aS0 + (size_t)16 * 768;
  const char* aS2 = aS0 + (size_t)32 * 768;
  const char* aS3 = aS0 + (size_t)48 * 768;
  const int nb = n0 + w * 32 + (lane >> 2);
  const char* bS0 = (const char*)wp + (size_t)nb * 768 + sle;
  const char* bS1 = (const char*)wp + (size_t)(nb + 16) * 768 + sle;
  const int aD = w * 2048 + lane * 8;
  const int bD = w * 1024 + lane * 8;
  f32x4 acc[8][4];
#pragma unroll
  for (int i = 0; i < 8; ++i)
#pragma unroll
    for (int j = 0; j < 4; ++j) acc[i][j] = (f32x4)(0.f);
  GEMM_PIPE(12);
#pragma unroll
  for (int mi = 0; mi < 8; ++mi) {
#pragma unroll
    for (int r = 0; r < 4; ++r) {
      int rr = wr * 128 + mi * 16 + ((lane >> 4) << 2) + r;
      int gl = bm * 256 + rr;
      int gr = gather_row(wc0 + (gl >> 6), gl & 63);
#pragma unroll
      for (int nj = 0; nj < 4; ++nj) {
        int nc = n0 + wc * 64 + nj * 16 + (lane & 15);
        size_t idx = (size_t)gr * 384 + nc;
        x2[idx] = acc[mi][nj][r] + pb[nc] + x[idx];
      }
    }
  }
}

// ---------------- fc1 GEMM (bf16 MFMA) + GELU -> bf16 hm ----------------
__global__ __launch_bounds__(256, 2) void fc1_mfma_k(
    const ushort* __restrict__ x2ln, const ushort* __restrict__ w1,
    const float* __restrict__ fb, ushort* __restrict__ hm, int row0) {
  __shared__ __align__(16) ushort As[3][8192];
  __shared__ __align__(16) ushort Bs[3][4096];
  const int tid = threadIdx.x;
  const int w = tid >> 6, lane = tid & 63;
  const int wr = w >> 1, wc = w & 1;
  const int bm = blockIdx.x, n0 = blockIdx.y * 128;
  const int sle = (((lane & 3) ^ ((lane >> 3) & 3)) << 4);
  const int rb = row0 + bm * 256 + w * 64 + (lane >> 2);
  const char* aS0 = (const char*)x2ln + (size_t)rb * 768 + sle;
  const char* aS1 = aS0 + (size_t)16 * 768;
  const char* aS2 = aS0 + (size_t)32 * 768;
  const char* aS3 = aS0 + (size_t)48 * 768;
  const int nb = n0 + w * 32 + (lane >> 2);
  const char* bS0 = (const char*)w1 + (size_t)nb * 768 + sle;
  const char* bS1 = (const char*)w1 + (size_t)(nb + 16) * 768 + sle;
  const int aD = w * 2048 + lane * 8;
  const int bD = w * 1024 + lane * 8;
  f32x4 acc[8][4];
#pragma unroll
  for (int i = 0; i < 8; ++i)
#pragma unroll
    for (int j = 0; j < 4; ++j) acc[i][j] = (f32x4)(0.f);
  GEMM_PIPE(12);
#pragma unroll
  for (int mi = 0; mi < 8; ++mi) {
#pragma unroll
    for (int r = 0; r < 4; ++r) {
      int rr = wr * 128 + mi * 16 + ((lane >> 4) << 2) + r;
      size_t lrow = (size_t)(bm * 256 + rr);
#pragma unroll
      for (int nj = 0; nj < 4; ++nj) {
        int nc = n0 + wc * 64 + nj * 16 + (lane & 15);
        float v = acc[mi][nj][r] + fb[nc];
        v = 0.5f * v * (1.f + erff(v * 0.70710678118654752f));
        hm[lrow * 1536 + nc] = f2bf(v);
      }
    }
  }
}

// ---------------- fc2 GEMM (bf16 MFMA) + residual into out ----------------
__global__ __launch_bounds__(256, 2) void fc2_mfma_k(
    const ushort* __restrict__ hm, const ushort* __restrict__ w2,
    const float* __restrict__ fb, float* __restrict__ out, int row0) {
  __shared__ __align__(16) ushort As[3][8192];
  __shared__ __align__(16) ushort Bs[3][4096];
  const int tid = threadIdx.x;
  const int w = tid >> 6, lane = tid & 63;
  const int wr = w >> 1, wc = w & 1;
  const int bm = blockIdx.x, n0 = blockIdx.y * 128;
  const int sle = (((lane & 3) ^ ((lane >> 3) & 3)) << 4);
  const int rb = bm * 256 + w * 64 + (lane >> 2);
  const char* aS0 = (const char*)hm + (size_t)rb * 3072 + sle;
  const char* aS1 = aS0 + (size_t)16 * 3072;
  const char* aS2 = aS0 + (size_t)32 * 3072;
  const char* aS3 = aS0 + (size_t)48 * 3072;
  const int nb = n0 + w * 32 + (lane >> 2);
  const char* bS0 = (const char*)w2 + (size_t)nb * 3072 + sle;
  const char* bS1 = (const char*)w2 + (size_t)(nb + 16) * 3072 + sle;
  const int aD = w * 2048 + lane * 8;
  const int bD = w * 1024 + lane * 8;
  f32x4 acc[8][4];
#pragma unroll
  for (int i = 0; i < 8; ++i)
#pragma unroll
    for (int j = 0; j < 4; ++j) acc[i][j] = (f32x4)(0.f);
  GEMM_PIPE(48);
#pragma unroll
  for (int mi = 0; mi < 8; ++mi) {
#pragma unroll
    for (int r = 0; r < 4; ++r) {
      int rr = wr * 128 + mi * 16 + ((lane >> 4) << 2) + r;
      size_t grow = (size_t)(row0 + bm * 256 + rr);
#pragma unroll
      for (int nj = 0; nj < 4; ++nj) {
        int nc = n0 + wc * 64 + nj * 16 + (lane & 15);
        size_t idx = grow * 384 + nc;
        out[idx] = out[idx] + acc[mi][nj][r] + fb[nc];
      }
    }
  }
}

extern "C" void kernel_launch(void* const* d_in, const int* in_sizes, int n_in,
                              void* d_out, int out_size, void* d_ws, size_t ws_size,
                              hipStream_t stream) {
  const float* x = (const float*)d_in[0];
  const float* qkv_w = (const float*)d_in[1];
  const float* qkv_b = (const float*)d_in[2];
  const float* proj_w = (const float*)d_in[3];
  const float* proj_b = (const float*)d_in[4];
  const float* rpb = (const float*)d_in[5];
  const float* n1g = (const float*)d_in[6];
  const float* n1b = (const float*)d_in[7];
  const float* n2g = (const float*)d_in[8];
  const float* n2b = (const float*)d_in[9];
  const float* fc1w = (const float*)d_in[10];
  const float* fc1b = (const float*)d_in[11];
  const float* fc2w = (const float*)d_in[12];
  const float* fc2b = (const float*)d_in[13];
  float* out = (float*)d_out;
  char* ws = (char*)d_ws;

  ushort* wq = (ushort*)ws;                              // [1152][384]
  ushort* wp = wq + 442368;                              // [384][384]
  ushort* w1 = wp + 147456;                              // [1536][384]
  ushort* w2 = w1 + 589824;                              // [384][1536]
  ushort* xln = (ushort*)(ws + 3538944);                 // 100663296 B
  char* scratch = ws + 3538944 + 100663296;
  size_t base = 3538944 + 100663296;
  size_t ssz = (ws_size > base) ? ws_size - base : 0;

  wprep_k<<<6912, 256, 0, stream>>>(qkv_w, proj_w, fc1w, fc2w, wq, wp, w1, w2);
  ln_fused_k<<<ROWS_TOTAL / 4, 256, 0, stream>>>(x, n1g, n1b, xln);

  // attention phase, chunked over windows (4-window granularity)
  const size_t perwin = 344064;  // q,k,v fp32 (3*98304B) + ao bf16 (49152B)
  int nwc = (int)(ssz / perwin);
  if (nwc > NWIN_TOTAL) nwc = NWIN_TOTAL;
  nwc &= ~3;
  if (nwc < 4) nwc = 4;
  float* qd = (float*)scratch;
  float* kd = qd + (size_t)nwc * 24576;
  float* vd = kd + (size_t)nwc * 24576;
  ushort* ao = (ushort*)(vd + (size_t)nwc * 24576);
  for (int wc0 = 0; wc0 < NWIN_TOTAL; wc0 += nwc) {
    int nw = (NWIN_TOTAL - wc0 < nwc) ? (NWIN_TOTAL - wc0) : nwc;
    qkv_mfma_k<<<dim3(nw / 4, 9), 256, 0, stream>>>(xln, wq, qkv_b, qd, kd, vd, wc0);
    attn_k<<<dim3(nw, 6), 128, 0, stream>>>(qd, kd, vd, rpb, ao, wc0);
    proj_mfma_k<<<dim3(nw / 4, 3), 256, 0, stream>>>(ao, wp, proj_b, x, out, wc0);
  }

  // MLP phase
  ln_fused_k<<<ROWS_TOTAL / 4, 256, 0, stream>>>(out, n2g, n2b, xln);
  const size_t pergrp = 786432;  // 256 rows * 1536 * 2B
  int ngc = (int)(ssz / pergrp);
  if (ngc > 512) ngc = 512;
  if (ngc < 1) ngc = 1;
  ushort* hm = (ushort*)scratch;
  for (int g0 = 0; g0 < 512; g0 += ngc) {
    int ng = (512 - g0 < ngc) ? (512 - g0) : ngc;
    fc1_mfma_k<<<dim3(ng, 12), 256, 0, stream>>>(xln, w1, fc1b, hm, g0 * 256);
    fc2_mfma_k<<<dim3(ng, 3), 256, 0, stream>>>(hm, w2, fc2b, out, g0 * 256);
  }
}